// Round 7
// baseline (895.740 us; speedup 1.0000x reference)
//
#include <hip/hip_runtime.h>
#include <hip/hip_bf16.h>

#define B_ 4096
#define N_ 30
#define D_ 512
#define H_ 4
#define M_ (B_*N_)      // 122880 tokens
#define PE_ROWS 31

typedef unsigned short u16;
typedef __attribute__((ext_vector_type(8))) short bf16x8;
typedef __attribute__((ext_vector_type(4))) float f32x4;

__device__ __forceinline__ float bf2f(u16 s) { return __uint_as_float(((unsigned)s) << 16); }
__device__ __forceinline__ u16 f2bf(float f) {
  __hip_bfloat16 h = __float2bfloat16(f);
  return *reinterpret_cast<u16*>(&h);
}

// fast tanh: 1 - 2/(exp(2x)+1)
__device__ __forceinline__ float ftanh(float x) {
  float e = __expf(2.f * x);
  return 1.f - 2.f * __builtin_amdgcn_rcpf(e + 1.f);
}

// async global->LDS, 16B per lane. LDS dest = wave-uniform base + lane*16.
__device__ __forceinline__ void gll16(const void* g, void* l) {
  __builtin_amdgcn_global_load_lds(
      (const __attribute__((address_space(1))) unsigned int*)g,
      (__attribute__((address_space(3))) unsigned int*)l, 16, 0, 0);
}

// full-wave (64-lane) sum / max
__device__ __forceinline__ float wsum(float v) {
  #pragma unroll
  for (int m = 32; m >= 1; m >>= 1) v += __shfl_xor(v, m);
  return v;
}
__device__ __forceinline__ float wmax(float v) {
  #pragma unroll
  for (int m = 32; m >= 1; m >>= 1) v = fmaxf(v, __shfl_xor(v, m));
  return v;
}

// block-wide sum over 512 threads
__device__ __forceinline__ float bsum512(float v, float* red) {
  int lane = threadIdx.x & 63;
  int w = threadIdx.x >> 6;
  #pragma unroll
  for (int m = 32; m >= 1; m >>= 1) v += __shfl_xor(v, m);
  if (lane == 0) red[w] = v;
  __syncthreads();
  if (threadIdx.x < 64) {
    float t = (lane < 8) ? red[lane] : 0.0f;
    #pragma unroll
    for (int m = 4; m >= 1; m >>= 1) t += __shfl_xor(t, m);
    if (lane == 0) red[0] = t;
  }
  __syncthreads();
  float r = red[0];
  __syncthreads();
  return r;
}

// K1: wave-per-token prep (normalize -> LN1 -> +pos_emb, pools, cosine).
// Emits x1 (bf16), mp (bf16, for MFMA k2), mpx (f32), cos.
__global__ __launch_bounds__(512) void k1_prep(
    const float* __restrict__ x, const int* __restrict__ order,
    const float* __restrict__ ndocs, const float* __restrict__ dw,
    const float* __restrict__ pe, const float* __restrict__ g1,
    const float* __restrict__ bln1,
    u16* __restrict__ x1bf, u16* __restrict__ mpbf, float* __restrict__ mpx,
    float* __restrict__ cosb) {
  __shared__ float lds_mp[8*512];
  __shared__ float lds_mpx[8*512];
  __shared__ float xps[32];
  int b = blockIdx.x;
  int tid = threadIdx.x;
  int wid = tid >> 6, lane = tid & 63;
  int d0 = lane * 8;
  float g[8], bl[8];
  *(float4*)&g[0]  = *(const float4*)&g1[d0];
  *(float4*)&g[4]  = *(const float4*)&g1[d0+4];
  *(float4*)&bl[0] = *(const float4*)&bln1[d0];
  *(float4*)&bl[4] = *(const float4*)&bln1[d0+4];
  float xp_reg[4][8];
  float accmp[8] = {0,0,0,0,0,0,0,0}, accmpx[8] = {0,0,0,0,0,0,0,0};
  #pragma unroll
  for (int t = 0; t < 4; ++t) {
    int n = wid + 8*t;
    if (n < N_) {
      int tok = b*N_ + n;
      float v[8];
      *(float4*)&v[0] = *(const float4*)&x[(size_t)tok*D_ + d0];
      *(float4*)&v[4] = *(const float4*)&x[(size_t)tok*D_ + d0 + 4];
      float ss = 0.f;
      #pragma unroll
      for (int i = 0; i < 8; ++i) ss += v[i]*v[i];
      ss = wsum(ss);
      float inv = 1.f / fmaxf(sqrtf(ss), 1e-8f);
      float mu = 0.f;
      #pragma unroll
      for (int i = 0; i < 8; ++i) { v[i] *= inv; mu += v[i]; }
      mu = wsum(mu) * (1.f/D_);
      float m2 = ss*inv*inv*(1.f/D_);
      float rs = 1.f / sqrtf(m2 - mu*mu + 1e-5f);
      int o = order[tok];
      float p8[8];
      *(float4*)&p8[0] = *(const float4*)&pe[(size_t)o*D_ + d0];
      *(float4*)&p8[4] = *(const float4*)&pe[(size_t)o*D_ + d0 + 4];
      float wv = dw[tok];
      float sq = 0.f;
      bf16x8 xb;
      #pragma unroll
      for (int i = 0; i < 8; ++i) {
        float x1v = g[i]*((v[i]-mu)*rs) + bl[i];
        xb[i] = (short)f2bf(x1v);
        float xpv = x1v + p8[i];
        xp_reg[t][i] = xpv;
        accmp[i]  += wv*xpv;
        accmpx[i] += wv*x1v;
        sq += xpv*xpv;
      }
      *(bf16x8*)&x1bf[(size_t)tok*D_ + d0] = xb;
      sq = wsum(sq);
      if (lane == 0) xps[n] = sq;
    }
  }
  #pragma unroll
  for (int i = 0; i < 8; i += 4) {
    *(float4*)&lds_mp[wid*512 + d0 + i]  = *(float4*)&accmp[i];
    *(float4*)&lds_mpx[wid*512 + d0 + i] = *(float4*)&accmpx[i];
  }
  __syncthreads();
  float invnd = 1.f / ndocs[b];
  float mpv[8] = {0,0,0,0,0,0,0,0}, mpxv[8] = {0,0,0,0,0,0,0,0};
  #pragma unroll
  for (int w = 0; w < 8; ++w) {
    #pragma unroll
    for (int i = 0; i < 8; i += 4) {
      float4 a = *(float4*)&lds_mp[w*512 + d0 + i];
      mpv[i+0] += a.x; mpv[i+1] += a.y; mpv[i+2] += a.z; mpv[i+3] += a.w;
      float4 c = *(float4*)&lds_mpx[w*512 + d0 + i];
      mpxv[i+0] += c.x; mpxv[i+1] += c.y; mpxv[i+2] += c.z; mpxv[i+3] += c.w;
    }
  }
  #pragma unroll
  for (int i = 0; i < 8; ++i) { mpv[i] *= invnd; mpxv[i] *= invnd; }
  if (wid == 0) {
    bf16x8 mb;
    #pragma unroll
    for (int i = 0; i < 8; ++i) mb[i] = (short)f2bf(mpv[i]);
    *(bf16x8*)&mpbf[(size_t)b*D_ + d0] = mb;
  }
  if (wid == 1) {
    #pragma unroll
    for (int i = 0; i < 8; i += 4)
      *(float4*)&mpx[(size_t)b*D_ + d0 + i] = *(float4*)&mpxv[i];
  }
  float mn = 0.f;
  #pragma unroll
  for (int i = 0; i < 8; ++i) mn += mpv[i]*mpv[i];
  float mpn = sqrtf(wsum(mn));
  #pragma unroll
  for (int t = 0; t < 4; ++t) {
    int n = wid + 8*t;
    if (n < N_) {
      float dot = 0.f;
      #pragma unroll
      for (int i = 0; i < 8; ++i) dot += mpv[i]*xp_reg[t][i];
      dot = wsum(dot);
      if (lane == 0)
        cosb[b*N_ + n] = dot / fmaxf(mpn * sqrtf(xps[n]), 1e-8f);
    }
  }
}

// peW[p][j] = pos_emb[p] @ W_top   (31 x 512)
__global__ __launch_bounds__(512) void k_pew(
    const float* __restrict__ pe, const float* __restrict__ w1,
    float* __restrict__ peW) {
  int p = blockIdx.x, j = threadIdx.x;
  float acc = 0.f;
  for (int dd = 0; dd < D_; ++dd) acc += pe[p*D_ + dd] * w1[(size_t)dd*D_ + j];
  peW[p*D_ + j] = acc;
}

// Tiled transpose+convert: out[j][k] = bf16(in[k][j])
__global__ __launch_bounds__(256) void k_tcvt(
    const float* __restrict__ in, u16* __restrict__ out, int Kdim, int Jdim) {
  __shared__ float tile[64][65];
  int k0 = blockIdx.x * 64, j0 = blockIdx.y * 64;
  int t = threadIdx.x;
  int tr = t >> 4, tc4 = (t & 15) * 4;
  #pragma unroll
  for (int i = 0; i < 4; ++i) {
    int k = k0 + tr + i*16;
    float4 v = *(const float4*)&in[(size_t)k*Jdim + j0 + tc4];
    tile[tr + i*16][tc4+0] = v.x;
    tile[tr + i*16][tc4+1] = v.y;
    tile[tr + i*16][tc4+2] = v.z;
    tile[tr + i*16][tc4+3] = v.w;
  }
  __syncthreads();
  #pragma unroll
  for (int i = 0; i < 4; ++i) {
    int j = tr + i*16;
    uint2 u;
    u.x = (unsigned)f2bf(tile[tc4+0][j]) | ((unsigned)f2bf(tile[tc4+1][j]) << 16);
    u.y = (unsigned)f2bf(tile[tc4+2][j]) | ((unsigned)f2bf(tile[tc4+3][j]) << 16);
    *(uint2*)&out[(size_t)(j0+j)*Kdim + k0 + tc4] = u;
  }
}

// K2 v3: mpW = mp @ W_mid + b1, MFMA 128x128 tile, BK=64, 128 blocks.
__global__ __launch_bounds__(256, 3) void k2_mpw(
    const u16* __restrict__ mpbf, const u16* __restrict__ w1mT,
    const float* __restrict__ b1, float* __restrict__ mpW) {
  __shared__ __align__(16) u16 As[128*64];
  __shared__ __align__(16) u16 Bs[128*64];
  int tid = threadIdx.x;
  int lane = tid & 63, wid = tid >> 6;
  int wg = (blockIdx.x & 7)*16 + (blockIdx.x >> 3);   // bijective XCD swizzle
  int colb = wg & 3, rowb = wg >> 2;
  int row0 = rowb*128, col0 = colb*128;
  int wm = wid >> 1, wn = wid & 1;
  int lr = lane & 15, lk = lane >> 4;
  int srow = lane >> 3;
  int skel = ((lane & 7) ^ srow) << 3;
  f32x4 acc[4][4];
  #pragma unroll
  for (int nf = 0; nf < 4; ++nf) {
    float bv = b1[col0 + wn*64 + nf*16 + lr];
    #pragma unroll
    for (int mf = 0; mf < 4; ++mf)
      acc[mf][nf] = (f32x4){bv, bv, bv, bv};
  }
  for (int k0 = 0; k0 < D_; k0 += 64) {
    __syncthreads();
    #pragma unroll
    for (int i = 0; i < 4; ++i) {
      int rb = wid*32 + i*8;
      gll16(&mpbf[(size_t)(row0 + rb + srow)*D_ + k0 + skel], &As[rb*64]);
      gll16(&w1mT[(size_t)(col0 + rb + srow)*D_ + k0 + skel], &Bs[rb*64]);
    }
    __syncthreads();
    #pragma unroll
    for (int kk = 0; kk < 2; ++kk) {
      int kb = (kk*64 + lk*16) ^ ((lr & 7) << 4);
      bf16x8 a[4];
      #pragma unroll
      for (int mf = 0; mf < 4; ++mf)
        a[mf] = *(const bf16x8*)((const char*)As + (wm*64 + mf*16 + lr)*128 + kb);
      #pragma unroll
      for (int nf = 0; nf < 4; ++nf) {
        bf16x8 bfr = *(const bf16x8*)((const char*)Bs + (wn*64 + nf*16 + lr)*128 + kb);
        #pragma unroll
        for (int mf = 0; mf < 4; ++mf)
          acc[mf][nf] = __builtin_amdgcn_mfma_f32_16x16x32_bf16(a[mf], bfr, acc[mf][nf], 0, 0, 0);
      }
    }
  }
  #pragma unroll
  for (int mf = 0; mf < 4; ++mf)
    #pragma unroll
    for (int nf = 0; nf < 4; ++nf)
      #pragma unroll
      for (int r = 0; r < 4; ++r) {
        int m = row0 + wm*64 + mf*16 + lk*4 + r;
        int j = col0 + wn*64 + nf*16 + lr;
        mpW[(size_t)m*D_ + j] = acc[mf][nf][r];
      }
}

// K4 v6: BM=256, BN=256, BK=64; 512 thr / 8 waves (2M x 4N, wave 128x64).
// global_load_lds staging + both-sides swizzle; additive terms in acc init;
// XCD-bijective swizzle pairs the 2 col-blocks of a row on one XCD.
__global__ __launch_bounds__(512, 4) void k4_fc1(
    const u16* __restrict__ x1bf, const u16* __restrict__ w1T,
    const float* __restrict__ w1, const float* __restrict__ w2,
    const int* __restrict__ order, const float* __restrict__ cosb,
    const float* __restrict__ mpW, const float* __restrict__ peW,
    float* __restrict__ Zp) {
  __shared__ __align__(16) u16 As[256*64];   // 32 KB
  __shared__ __align__(16) u16 Bs[256*64];   // 32 KB
  int tid = threadIdx.x;
  int lane = tid & 63, wid = tid >> 6;
  int wg = (blockIdx.x & 7)*120 + (blockIdx.x >> 3);  // 960 blocks, bijective
  int colb = wg & 1;
  int col0 = colb * 256;
  int row0 = (wg >> 1) * 256;
  int wm = wid >> 2, wn = wid & 3;
  int lr = lane & 15, lk = lane >> 4;
  int srow = lane >> 3;
  int skel = ((lane & 7) ^ srow) << 3;
  float wl[4];
  #pragma unroll
  for (int nf = 0; nf < 4; ++nf)
    wl[nf] = w1[(size_t)1024*D_ + col0 + wn*64 + nf*16 + lr];
  f32x4 acc[8][4];
  #pragma unroll
  for (int mf = 0; mf < 8; ++mf) {
    #pragma unroll
    for (int r = 0; r < 4; ++r) {
      int m = row0 + wm*128 + mf*16 + lk*4 + r;
      int bidx = m / N_;
      int o = order[m];
      float cs = cosb[m];
      #pragma unroll
      for (int nf = 0; nf < 4; ++nf) {
        int jl = col0 + wn*64 + nf*16 + lr;
        acc[mf][nf][r] = mpW[(size_t)bidx*D_ + jl] + peW[o*D_ + jl] + cs*wl[nf];
      }
    }
  }
  for (int k0 = 0; k0 < D_; k0 += 64) {
    __syncthreads();
    #pragma unroll
    for (int i = 0; i < 4; ++i) {
      int rb = wid*32 + i*8;
      gll16(&x1bf[(size_t)(row0 + rb + srow)*D_ + k0 + skel], &As[rb*64]);
      gll16(&w1T [(size_t)(col0 + rb + srow)*D_ + k0 + skel], &Bs[rb*64]);
    }
    __syncthreads();
    #pragma unroll
    for (int kk = 0; kk < 2; ++kk) {
      int kb = (kk*64 + lk*16) ^ ((lr & 7) << 4);
      bf16x8 a[8];
      #pragma unroll
      for (int mf = 0; mf < 8; ++mf)
        a[mf] = *(const bf16x8*)((const char*)As + (wm*128 + mf*16 + lr)*128 + kb);
      #pragma unroll
      for (int nf = 0; nf < 4; ++nf) {
        bf16x8 bfr = *(const bf16x8*)((const char*)Bs + (wn*64 + nf*16 + lr)*128 + kb);
        #pragma unroll
        for (int mf = 0; mf < 8; ++mf)
          acc[mf][nf] = __builtin_amdgcn_mfma_f32_16x16x32_bf16(a[mf], bfr, acc[mf][nf], 0, 0, 0);
      }
    }
  }
  // epilogue: tanh + w2-dot, reduce 16-lane col groups, then cross-wn in LDS
  float w2r[4][4];
  #pragma unroll
  for (int nf = 0; nf < 4; ++nf)
    *(float4*)w2r[nf] = *(const float4*)&w2[(col0 + wn*64 + nf*16 + lr)*4];
  __syncthreads();                 // all LDS frag reads done -> alias zred
  float* zred = (float*)As;        // [4][256][4] = 16 KB
  #pragma unroll
  for (int mf = 0; mf < 8; ++mf) {
    #pragma unroll
    for (int r = 0; r < 4; ++r) {
      int rowt = wm*128 + mf*16 + lk*4 + r;
      float z0=0.f, z1=0.f, z2=0.f, z3=0.f;
      #pragma unroll
      for (int nf = 0; nf < 4; ++nf) {
        float t = ftanh(acc[mf][nf][r]);
        z0 += t * w2r[nf][0]; z1 += t * w2r[nf][1];
        z2 += t * w2r[nf][2]; z3 += t * w2r[nf][3];
      }
      #pragma unroll
      for (int msk = 1; msk <= 8; msk <<= 1) {
        z0 += __shfl_xor(z0, msk); z1 += __shfl_xor(z1, msk);
        z2 += __shfl_xor(z2, msk); z3 += __shfl_xor(z3, msk);
      }
      if (lr == 0)
        *(float4*)&zred[(wn*256 + rowt)*4] = make_float4(z0, z1, z2, z3);
    }
  }
  __syncthreads();
  if (tid < 256) {
    float4 s0 = *(float4*)&zred[tid*4];
    float4 s1 = *(float4*)&zred[(256 + tid)*4];
    float4 s2 = *(float4*)&zred[(512 + tid)*4];
    float4 s3 = *(float4*)&zred[(768 + tid)*4];
    *(float4*)&Zp[((size_t)colb*M_ + row0 + tid)*4] =
        make_float4(s0.x+s1.x+s2.x+s3.x, s0.y+s1.y+s2.y+s3.y,
                    s0.z+s1.z+s2.z+s3.z, s0.w+s1.w+s2.w+s3.w);
  }
}

// K5: wave-per-batch. Sums 2 Zp partials; in-wave softmax; bf16x8 pooling;
// LN2 -> Hh2 bf16 + head-mean f32.
__global__ __launch_bounds__(512) void k5_attn(
    const float* __restrict__ Zp, const float* __restrict__ b2,
    const unsigned char* __restrict__ amask, const u16* __restrict__ x1bf,
    const float* __restrict__ mpx, const float* __restrict__ g2,
    const float* __restrict__ bln2, u16* __restrict__ Hh2bf,
    float* __restrict__ hmean) {
  __shared__ float abuf[8][120];
  int tid = threadIdx.x;
  int wid = tid >> 6, lane = tid & 63;
  int b = blockIdx.x*8 + wid;
  bool act = lane < N_;
  int tok = b*N_ + (act ? lane : 0);
  float zz[4] = {-INFINITY, -INFINITY, -INFINITY, -INFINITY};
  if (act) {
    float4 za = *(const float4*)&Zp[(size_t)tok*4];
    float4 zb = *(const float4*)&Zp[((size_t)M_ + tok)*4];
    float4 bv = *(const float4*)b2;
    zz[0] = za.x+zb.x+bv.x; zz[1] = za.y+zb.y+bv.y;
    zz[2] = za.z+zb.z+bv.z; zz[3] = za.w+zb.w+bv.w;
    if (amask[tok]) { zz[0]=zz[1]=zz[2]=zz[3]=-INFINITY; }
  }
  float p[4];
  #pragma unroll
  for (int h = 0; h < 4; ++h) {
    float mx = wmax(zz[h]);
    float e = act ? __expf(zz[h] - mx) : 0.f;
    float s = wsum(e);
    p[h] = e / s;
  }
  if (act) *(float4*)&abuf[wid][lane*4] = make_float4(p[0], p[1], p[2], p[3]);
  __syncthreads();
  float hv[4][8] = {};
  const u16* xr = &x1bf[(size_t)b*N_*D_ + lane*8];
  for (int j = 0; j < N_; ++j) {
    bf16x8 xb = *(const bf16x8*)(xr + (size_t)j*D_);
    float xv[8];
    #pragma unroll
    for (int e = 0; e < 8; ++e) xv[e] = bf2f((u16)xb[e]);
    #pragma unroll
    for (int i = 0; i < 4; ++i) {
      float a = abuf[wid][i*N_ + j];
      #pragma unroll
      for (int e = 0; e < 8; ++e) hv[i][e] += a * xv[e];
    }
  }
  float mpxv[8];
  *(float4*)&mpxv[0] = *(const float4*)&mpx[(size_t)b*D_ + lane*8];
  *(float4*)&mpxv[4] = *(const float4*)&mpx[(size_t)b*D_ + lane*8 + 4];
  float s1 = 0.f, s2 = 0.f;
  #pragma unroll
  for (int i = 0; i < 4; ++i)
    #pragma unroll
    for (int e = 0; e < 8; ++e) {
      hv[i][e] += mpxv[e];
      s1 += hv[i][e];
      s2 += hv[i][e]*hv[i][e];
    }
  s1 = wsum(s1); s2 = wsum(s2);
  float mu = s1 * (1.f/2048.f);
  float var = s2 * (1.f/2048.f) - mu*mu;
  float rs = 1.f / sqrtf(var + 1e-5f);
  float hm[8] = {0,0,0,0,0,0,0,0};
  #pragma unroll
  for (int i = 0; i < 4; ++i) {
    int idx = i*D_ + lane*8;
    float gg[8], bb[8];
    *(float4*)&gg[0] = *(const float4*)&g2[idx];
    *(float4*)&gg[4] = *(const float4*)&g2[idx+4];
    *(float4*)&bb[0] = *(const float4*)&bln2[idx];
    *(float4*)&bb[4] = *(const float4*)&bln2[idx+4];
    bf16x8 ob;
    #pragma unroll
    for (int e = 0; e < 8; ++e) {
      float v = gg[e]*((hv[i][e]-mu)*rs) + bb[e];
      hm[e] += v;
      ob[e] = (short)f2bf(v);
    }
    *(bf16x8*)&Hh2bf[(size_t)b*2048 + idx] = ob;
  }
  #pragma unroll
  for (int e = 0; e < 8; ++e) hm[e] *= 0.25f;
  *(float4*)&hmean[(size_t)b*D_ + lane*8]     = *(float4*)&hm[0];
  *(float4*)&hmean[(size_t)b*D_ + lane*8 + 4] = *(float4*)&hm[4];
}

// K6 v4: fc2 GEMM 128x128 tile, BK=64, split-K=4 -> 512 blocks.
__global__ __launch_bounds__(256, 3) void k6_fc2(
    const u16* __restrict__ Hh2bf, const u16* __restrict__ fwT,
    float* __restrict__ pred_p) {
  __shared__ __align__(16) u16 As[128*64];
  __shared__ __align__(16) u16 Bs[128*64];
  int tid = threadIdx.x;
  int lane = tid & 63, wid = tid >> 6;
  int wg = (blockIdx.x & 7)*64 + (blockIdx.x >> 3);   // 512 blocks bijective
  int kz = wg >> 7;
  int rem = wg & 127;
  int rowb = rem >> 2, colb = rem & 3;
  int row0 = rowb*128, col0 = colb*128;
  int kbase = kz*512;
  int wm = wid >> 1, wn = wid & 1;
  int lr = lane & 15, lk = lane >> 4;
  int srow = lane >> 3;
  int skel = ((lane & 7) ^ srow) << 3;
  f32x4 acc[4][4] = {};
  for (int k0 = kbase; k0 < kbase + 512; k0 += 64) {
    __syncthreads();
    #pragma unroll
    for (int i = 0; i < 4; ++i) {
      int rb = wid*32 + i*8;
      gll16(&Hh2bf[(size_t)(row0 + rb + srow)*2048 + k0 + skel], &As[rb*64]);
      gll16(&fwT  [(size_t)(col0 + rb + srow)*2048 + k0 + skel], &Bs[rb*64]);
    }
    __syncthreads();
    #pragma unroll
    for (int kk = 0; kk < 2; ++kk) {
      int kb = (kk*64 + lk*16) ^ ((lr & 7) << 4);
      bf16x8 a[4];
      #pragma unroll
      for (int mf = 0; mf < 4; ++mf)
        a[mf] = *(const bf16x8*)((const char*)As + (wm*64 + mf*16 + lr)*128 + kb);
      #pragma unroll
      for (int nf = 0; nf < 4; ++nf) {
        bf16x8 bfr = *(const bf16x8*)((const char*)Bs + (wn*64 + nf*16 + lr)*128 + kb);
        #pragma unroll
        for (int mf = 0; mf < 4; ++mf)
          acc[mf][nf] = __builtin_amdgcn_mfma_f32_16x16x32_bf16(a[mf], bfr, acc[mf][nf], 0, 0, 0);
      }
    }
  }
  float* dst = pred_p + (size_t)kz * B_ * D_;
  #pragma unroll
  for (int mf = 0; mf < 4; ++mf)
    #pragma unroll
    for (int nf = 0; nf < 4; ++nf)
      #pragma unroll
      for (int r = 0; r < 4; ++r) {
        int m = row0 + wm*64 + mf*16 + lk*4 + r;
        int j = col0 + wn*64 + nf*16 + lr;
        dst[(size_t)m*D_ + j] = acc[mf][nf][r];
      }
}

// K7: combine 4 split-K partials + fb, LN3, + head-mean, LN4 -> out
__global__ __launch_bounds__(512) void k7_final(
    const float* __restrict__ pred_p, const float* __restrict__ hmean,
    const float* __restrict__ fb,
    const float* __restrict__ g3, const float* __restrict__ b3,
    const float* __restrict__ g4, const float* __restrict__ b4,
    float* __restrict__ out) {
  __shared__ float red[8];
  int b = blockIdx.x, d = threadIdx.x;
  size_t i = (size_t)b*D_ + d;
  size_t BD = (size_t)B_*D_;
  float p = pred_p[i] + pred_p[BD + i] + pred_p[2*BD + i] + pred_p[3*BD + i]
          + fb[d];
  float s1 = bsum512(p, red);
  float s2 = bsum512(p*p, red);
  float mu = s1*(1.f/D_);
  float var = s2*(1.f/D_) - mu*mu;
  float p3 = g3[d]*((p-mu)/sqrtf(var+1e-5f)) + b3[d];
  float q = p3 + hmean[i];
  s1 = bsum512(q, red);
  s2 = bsum512(q*q, red);
  mu = s1*(1.f/D_);
  var = s2*(1.f/D_) - mu*mu;
  out[i] = g4[d]*((q-mu)/sqrtf(var+1e-5f)) + b4[d];
}

extern "C" void kernel_launch(void* const* d_in, const int* in_sizes, int n_in,
                              void* d_out, int out_size, void* d_ws, size_t ws_size,
                              hipStream_t stream) {
  const float* x      = (const float*)d_in[0];
  const unsigned char* amask = (const unsigned char*)d_in[1];
  const int*   order  = (const int*)d_in[2];
  const float* ndocs  = (const float*)d_in[3];
  const float* dw     = (const float*)d_in[4];
  const float* pe     = (const float*)d_in[6];
  const float* w1     = (const float*)d_in[7];
  const float* b1     = (const float*)d_in[8];
  const float* w2     = (const float*)d_in[9];
  const float* b2     = (const float*)d_in[10];
  const float* fw     = (const float*)d_in[11];
  const float* fb     = (const float*)d_in[12];
  const float* g1     = (const float*)d_in[13];
  const float* bln1   = (const float*)d_in[14];
  const float* g2     = (const float*)d_in[15];
  const float* bln2   = (const float*)d_in[16];
  const float* g3     = (const float*)d_in[17];
  const float* b3     = (const float*)d_in[18];
  const float* g4     = (const float*)d_in[19];
  const float* b4     = (const float*)d_in[20];
  float* out = (float*)d_out;

  char* ws = (char*)d_ws;
  size_t off = 0;
  u16*   x1bf   = (u16*)(ws + off);   off += (size_t)M_*D_*2;        // 125.8 MB
  u16*   mpbf   = (u16*)(ws + off);   off += (size_t)B_*D_*2;        // 4.2 MB
  float* mpx    = (float*)(ws + off); off += (size_t)B_*D_*4;        // 8.4 MB
  float* mpW    = (float*)(ws + off); off += (size_t)B_*D_*4;        // 8.4 MB
  float* hmean  = (float*)(ws + off); off += (size_t)B_*D_*4;        // 8.4 MB
  float* peW    = (float*)(ws + off); off += (size_t)PE_ROWS*D_*4;
  float* cosb   = (float*)(ws + off); off += (size_t)M_*4;
  float* Zp     = (float*)(ws + off); off += (size_t)2*M_*4*4;       // 3.9 MB
  float* pred_p = (float*)(ws + off); off += (size_t)4*B_*D_*4;      // 33.6 MB
  u16*   Hh2bf  = (u16*)(ws + off);   off += (size_t)B_*2048*2;      // 16.8 MB
  u16*   w1T    = (u16*)(ws + off);   off += (size_t)D_*D_*2;        // 0.5 MB
  u16*   w1mT   = (u16*)(ws + off);   off += (size_t)D_*D_*2;        // 0.5 MB
  u16*   fwT    = (u16*)(ws + off);   off += (size_t)D_*2048*2;      // 2.1 MB
  (void)ws_size; (void)in_sizes; (void)n_in; (void)out_size;

  k_tcvt<<<dim3(8, 8), 256, 0, stream>>>(w1, w1T, 512, 512);        // W_top^T
  k_tcvt<<<dim3(8, 8), 256, 0, stream>>>(w1 + 512*512, w1mT, 512, 512); // W_mid^T
  k_tcvt<<<dim3(32, 8), 256, 0, stream>>>(fw, fwT, 2048, 512);      // fc2_w^T
  k_pew<<<PE_ROWS, 512, 0, stream>>>(pe, w1, peW);
  k1_prep<<<B_, 512, 0, stream>>>(x, order, ndocs, dw, pe, g1, bln1,
                                  x1bf, mpbf, mpx, cosb);
  k2_mpw<<<128, 256, 0, stream>>>(mpbf, w1mT, b1, mpW);
  k4_fc1<<<960, 512, 0, stream>>>(x1bf, w1T, w1, w2, order, cosb,
                                  mpW, peW, Zp);
  k5_attn<<<B_/8, 512, 0, stream>>>(Zp, b2, amask, x1bf, mpx, g2, bln2,
                                    Hh2bf, hmean);
  k6_fc2<<<512, 256, 0, stream>>>(Hh2bf, fwT, pred_p);
  k7_final<<<B_, 512, 0, stream>>>(pred_p, hmean, fb, g3, b3, g4, b4, out);
}

// Round 8
// 428.685 us; speedup vs baseline: 2.0895x; 2.0895x over previous
//
#include <hip/hip_runtime.h>
#include <hip/hip_bf16.h>

#define B_ 4096
#define N_ 30
#define D_ 512
#define H_ 4
#define M_ (B_*N_)      // 122880 tokens
#define PE_ROWS 31

typedef unsigned short u16;
typedef __attribute__((ext_vector_type(8))) short bf16x8;
typedef __attribute__((ext_vector_type(4))) float f32x4;

__device__ __forceinline__ float bf2f(u16 s) { return __uint_as_float(((unsigned)s) << 16); }
__device__ __forceinline__ u16 f2bf(float f) {
  __hip_bfloat16 h = __float2bfloat16(f);
  return *reinterpret_cast<u16*>(&h);
}

// fast tanh: 1 - 2/(exp(2x)+1)
__device__ __forceinline__ float ftanh(float x) {
  float e = __expf(2.f * x);
  return 1.f - 2.f * __builtin_amdgcn_rcpf(e + 1.f);
}

// async global->LDS, 16B per lane. LDS dest = wave-uniform base + lane*16.
__device__ __forceinline__ void gll16(const void* g, void* l) {
  __builtin_amdgcn_global_load_lds(
      (const __attribute__((address_space(1))) unsigned int*)g,
      (__attribute__((address_space(3))) unsigned int*)l, 16, 0, 0);
}

// full-wave (64-lane) sum / max
__device__ __forceinline__ float wsum(float v) {
  #pragma unroll
  for (int m = 32; m >= 1; m >>= 1) v += __shfl_xor(v, m);
  return v;
}
__device__ __forceinline__ float wmax(float v) {
  #pragma unroll
  for (int m = 32; m >= 1; m >>= 1) v = fmaxf(v, __shfl_xor(v, m));
  return v;
}

// block-wide sum over 512 threads
__device__ __forceinline__ float bsum512(float v, float* red) {
  int lane = threadIdx.x & 63;
  int w = threadIdx.x >> 6;
  #pragma unroll
  for (int m = 32; m >= 1; m >>= 1) v += __shfl_xor(v, m);
  if (lane == 0) red[w] = v;
  __syncthreads();
  if (threadIdx.x < 64) {
    float t = (lane < 8) ? red[lane] : 0.0f;
    #pragma unroll
    for (int m = 4; m >= 1; m >>= 1) t += __shfl_xor(t, m);
    if (lane == 0) red[0] = t;
  }
  __syncthreads();
  float r = red[0];
  __syncthreads();
  return r;
}

// K1: wave-per-token prep (normalize -> LN1 -> +pos_emb, pools, cosine).
__global__ __launch_bounds__(512) void k1_prep(
    const float* __restrict__ x, const int* __restrict__ order,
    const float* __restrict__ ndocs, const float* __restrict__ dw,
    const float* __restrict__ pe, const float* __restrict__ g1,
    const float* __restrict__ bln1,
    u16* __restrict__ x1bf, u16* __restrict__ mpbf, float* __restrict__ mpx,
    float* __restrict__ cosb) {
  __shared__ float lds_mp[8*512];
  __shared__ float lds_mpx[8*512];
  __shared__ float xps[32];
  int b = blockIdx.x;
  int tid = threadIdx.x;
  int wid = tid >> 6, lane = tid & 63;
  int d0 = lane * 8;
  float g[8], bl[8];
  *(float4*)&g[0]  = *(const float4*)&g1[d0];
  *(float4*)&g[4]  = *(const float4*)&g1[d0+4];
  *(float4*)&bl[0] = *(const float4*)&bln1[d0];
  *(float4*)&bl[4] = *(const float4*)&bln1[d0+4];
  float xp_reg[4][8];
  float accmp[8] = {0,0,0,0,0,0,0,0}, accmpx[8] = {0,0,0,0,0,0,0,0};
  #pragma unroll
  for (int t = 0; t < 4; ++t) {
    int n = wid + 8*t;
    if (n < N_) {
      int tok = b*N_ + n;
      float v[8];
      *(float4*)&v[0] = *(const float4*)&x[(size_t)tok*D_ + d0];
      *(float4*)&v[4] = *(const float4*)&x[(size_t)tok*D_ + d0 + 4];
      float ss = 0.f, sm = 0.f;
      #pragma unroll
      for (int i = 0; i < 8; ++i) { ss += v[i]*v[i]; sm += v[i]; }
      ss = wsum(ss); sm = wsum(sm);   // independent trees, interleaved
      float inv = 1.f / fmaxf(sqrtf(ss), 1e-8f);
      float mu = sm * inv * (1.f/D_);
      float m2 = ss*inv*inv*(1.f/D_);
      float rs = 1.f / sqrtf(m2 - mu*mu + 1e-5f);
      int o = order[tok];
      float p8[8];
      *(float4*)&p8[0] = *(const float4*)&pe[(size_t)o*D_ + d0];
      *(float4*)&p8[4] = *(const float4*)&pe[(size_t)o*D_ + d0 + 4];
      float wv = dw[tok];
      float sq = 0.f;
      bf16x8 xb;
      #pragma unroll
      for (int i = 0; i < 8; ++i) {
        float x1v = g[i]*((v[i]*inv - mu)*rs) + bl[i];
        xb[i] = (short)f2bf(x1v);
        float xpv = x1v + p8[i];
        xp_reg[t][i] = xpv;
        accmp[i]  += wv*xpv;
        accmpx[i] += wv*x1v;
        sq += xpv*xpv;
      }
      *(bf16x8*)&x1bf[(size_t)tok*D_ + d0] = xb;
      sq = wsum(sq);
      if (lane == 0) xps[n] = sq;
    }
  }
  #pragma unroll
  for (int i = 0; i < 8; i += 4) {
    *(float4*)&lds_mp[wid*512 + d0 + i]  = *(float4*)&accmp[i];
    *(float4*)&lds_mpx[wid*512 + d0 + i] = *(float4*)&accmpx[i];
  }
  __syncthreads();
  float invnd = 1.f / ndocs[b];
  float mpv[8] = {0,0,0,0,0,0,0,0}, mpxv[8] = {0,0,0,0,0,0,0,0};
  #pragma unroll
  for (int w = 0; w < 8; ++w) {
    #pragma unroll
    for (int i = 0; i < 8; i += 4) {
      float4 a = *(float4*)&lds_mp[w*512 + d0 + i];
      mpv[i+0] += a.x; mpv[i+1] += a.y; mpv[i+2] += a.z; mpv[i+3] += a.w;
      float4 c = *(float4*)&lds_mpx[w*512 + d0 + i];
      mpxv[i+0] += c.x; mpxv[i+1] += c.y; mpxv[i+2] += c.z; mpxv[i+3] += c.w;
    }
  }
  #pragma unroll
  for (int i = 0; i < 8; ++i) { mpv[i] *= invnd; mpxv[i] *= invnd; }
  if (wid == 0) {
    bf16x8 mb;
    #pragma unroll
    for (int i = 0; i < 8; ++i) mb[i] = (short)f2bf(mpv[i]);
    *(bf16x8*)&mpbf[(size_t)b*D_ + d0] = mb;
  }
  if (wid == 1) {
    #pragma unroll
    for (int i = 0; i < 8; i += 4)
      *(float4*)&mpx[(size_t)b*D_ + d0 + i] = *(float4*)&mpxv[i];
  }
  float mn = 0.f;
  #pragma unroll
  for (int i = 0; i < 8; ++i) mn += mpv[i]*mpv[i];
  float mpn = sqrtf(wsum(mn));
  #pragma unroll
  for (int t = 0; t < 4; ++t) {
    int n = wid + 8*t;
    if (n < N_) {
      float dot = 0.f;
      #pragma unroll
      for (int i = 0; i < 8; ++i) dot += mpv[i]*xp_reg[t][i];
      dot = wsum(dot);
      if (lane == 0)
        cosb[b*N_ + n] = dot / fmaxf(mpn * sqrtf(xps[n]), 1e-8f);
    }
  }
}

// peW[p][j] = pos_emb[p] @ W_top   (31 x 512)
__global__ __launch_bounds__(512) void k_pew(
    const float* __restrict__ pe, const float* __restrict__ w1,
    float* __restrict__ peW) {
  int p = blockIdx.x, j = threadIdx.x;
  float acc = 0.f;
  for (int dd = 0; dd < D_; ++dd) acc += pe[p*D_ + dd] * w1[(size_t)dd*D_ + j];
  peW[p*D_ + j] = acc;
}

// Tiled transpose+convert: out[j][k] = bf16(in[k][j])
__global__ __launch_bounds__(256) void k_tcvt(
    const float* __restrict__ in, u16* __restrict__ out, int Kdim, int Jdim) {
  __shared__ float tile[64][65];
  int k0 = blockIdx.x * 64, j0 = blockIdx.y * 64;
  int t = threadIdx.x;
  int tr = t >> 4, tc4 = (t & 15) * 4;
  #pragma unroll
  for (int i = 0; i < 4; ++i) {
    int k = k0 + tr + i*16;
    float4 v = *(const float4*)&in[(size_t)k*Jdim + j0 + tc4];
    tile[tr + i*16][tc4+0] = v.x;
    tile[tr + i*16][tc4+1] = v.y;
    tile[tr + i*16][tc4+2] = v.z;
    tile[tr + i*16][tc4+3] = v.w;
  }
  __syncthreads();
  #pragma unroll
  for (int i = 0; i < 4; ++i) {
    int j = tr + i*16;
    uint2 u;
    u.x = (unsigned)f2bf(tile[tc4+0][j]) | ((unsigned)f2bf(tile[tc4+1][j]) << 16);
    u.y = (unsigned)f2bf(tile[tc4+2][j]) | ((unsigned)f2bf(tile[tc4+3][j]) << 16);
    *(uint2*)&out[(size_t)(j0+j)*Kdim + k0 + tc4] = u;
  }
}

// K2: mpW = mp @ W_mid + b1, MFMA 128x128 tile, BK=64, 128 blocks.
__global__ __launch_bounds__(256, 3) void k2_mpw(
    const u16* __restrict__ mpbf, const u16* __restrict__ w1mT,
    const float* __restrict__ b1, float* __restrict__ mpW) {
  __shared__ __align__(16) u16 As[128*64];
  __shared__ __align__(16) u16 Bs[128*64];
  int tid = threadIdx.x;
  int lane = tid & 63, wid = tid >> 6;
  int wg = (blockIdx.x & 7)*16 + (blockIdx.x >> 3);
  int colb = wg & 3, rowb = wg >> 2;
  int row0 = rowb*128, col0 = colb*128;
  int wm = wid >> 1, wn = wid & 1;
  int lr = lane & 15, lk = lane >> 4;
  int srow = lane >> 3;
  int skel = ((lane & 7) ^ srow) << 3;
  f32x4 acc[4][4];
  #pragma unroll
  for (int nf = 0; nf < 4; ++nf) {
    float bv = b1[col0 + wn*64 + nf*16 + lr];
    #pragma unroll
    for (int mf = 0; mf < 4; ++mf)
      acc[mf][nf] = (f32x4){bv, bv, bv, bv};
  }
  for (int k0 = 0; k0 < D_; k0 += 64) {
    __syncthreads();
    #pragma unroll
    for (int i = 0; i < 4; ++i) {
      int rb = wid*32 + i*8;
      gll16(&mpbf[(size_t)(row0 + rb + srow)*D_ + k0 + skel], &As[rb*64]);
      gll16(&w1mT[(size_t)(col0 + rb + srow)*D_ + k0 + skel], &Bs[rb*64]);
    }
    __syncthreads();
    #pragma unroll
    for (int kk = 0; kk < 2; ++kk) {
      int kb = (kk*64 + lk*16) ^ ((lr & 7) << 4);
      bf16x8 a[4];
      #pragma unroll
      for (int mf = 0; mf < 4; ++mf)
        a[mf] = *(const bf16x8*)((const char*)As + (wm*64 + mf*16 + lr)*128 + kb);
      #pragma unroll
      for (int nf = 0; nf < 4; ++nf) {
        bf16x8 bfr = *(const bf16x8*)((const char*)Bs + (wn*64 + nf*16 + lr)*128 + kb);
        #pragma unroll
        for (int mf = 0; mf < 4; ++mf)
          acc[mf][nf] = __builtin_amdgcn_mfma_f32_16x16x32_bf16(a[mf], bfr, acc[mf][nf], 0, 0, 0);
      }
    }
  }
  #pragma unroll
  for (int mf = 0; mf < 4; ++mf)
    #pragma unroll
    for (int nf = 0; nf < 4; ++nf)
      #pragma unroll
      for (int r = 0; r < 4; ++r) {
        int m = row0 + wm*64 + mf*16 + lk*4 + r;
        int j = col0 + wn*64 + nf*16 + lr;
        mpW[(size_t)m*D_ + j] = acc[mf][nf][r];
      }
}

// K4 v7: 128x128 m97-structure (round-6 v5, measured 143us) + LDS-staged
// acc-init (coalesced peW/mpW/order/cos/wl -> LDS, gathered via ds_read;
// replaces ~64 scattered global loads/thread) + bijective XCD chunking.
__global__ __launch_bounds__(256, 3) void k4_fc1(
    const u16* __restrict__ x1bf, const u16* __restrict__ w1T,
    const float* __restrict__ w1, const float* __restrict__ w2,
    const int* __restrict__ order, const float* __restrict__ cosb,
    const float* __restrict__ mpW, const float* __restrict__ peW,
    float* __restrict__ Zp) {
  __shared__ __align__(16) u16 As[128*64];   // 16 KB
  __shared__ __align__(16) u16 Bs[128*64];   // 16 KB
  __shared__ float zred[2*128*4];            // 4 KB
  int tid = threadIdx.x;
  int lane = tid & 63, wid = tid >> 6;
  int wg = (blockIdx.x & 7)*480 + (blockIdx.x >> 3);  // 3840 blocks bijective
  int colb = wg & 3, rowb = wg >> 2;
  int col0 = colb * 128;
  int row0 = rowb * 128;
  int wm = wid >> 1, wn = wid & 1;
  int lr = lane & 15, lk = lane >> 4;
  int srow = lane >> 3;
  int skel = ((lane & 7) ^ srow) << 3;
  // ---- acc-init staging (aliases As/Bs region; consumed before K-loop) ----
  float* peWs  = (float*)As;                 // [31][132] = 16.4 KB
  float* mpWs  = peWs + 31*132;              // [6][132]
  float* extra = mpWs + 6*132;               // wls[128] | cosbs[128] | orders
  float* wls   = extra;
  float* cosbs = extra + 128;
  int*   ords  = (int*)(extra + 256);        // [128]
  int bmin = row0 / N_;
  for (int idx = tid; idx < 31*128; idx += 256) {
    int p = idx >> 7, c = idx & 127;
    peWs[p*132 + c] = peW[p*D_ + col0 + c];
  }
  for (int idx = tid; idx < 6*128; idx += 256) {
    int s = idx >> 7, c = idx & 127;
    int bb = bmin + s; if (bb > B_-1) bb = B_-1;
    mpWs[s*132 + c] = mpW[(size_t)bb*D_ + col0 + c];
  }
  if (tid < 128) {
    wls[tid]   = w1[(size_t)1024*D_ + col0 + tid];
    cosbs[tid] = cosb[row0 + tid];
    ords[tid]  = order[row0 + tid];
  }
  __syncthreads();
  f32x4 acc[4][4];
  #pragma unroll
  for (int mf = 0; mf < 4; ++mf) {
    #pragma unroll
    for (int r = 0; r < 4; ++r) {
      int rowt = wm*64 + mf*16 + lk*4 + r;
      int bs = (row0 + rowt) / N_ - bmin;
      int o = ords[rowt];
      float cs = cosbs[rowt];
      #pragma unroll
      for (int nf = 0; nf < 4; ++nf) {
        int jl = wn*64 + nf*16 + lr;
        acc[mf][nf][r] = mpWs[bs*132 + jl] + peWs[o*132 + jl] + cs*wls[jl];
      }
    }
  }
  // w2 rows for epilogue (global, small)
  float w2r[4][4];
  #pragma unroll
  for (int nf = 0; nf < 4; ++nf)
    *(float4*)w2r[nf] = *(const float4*)&w2[(col0 + wn*64 + nf*16 + lr)*4];
  // ---- K-loop (m97 structure) ----
  for (int k0 = 0; k0 < D_; k0 += 64) {
    __syncthreads();
    #pragma unroll
    for (int i = 0; i < 4; ++i) {
      int rb = wid*32 + i*8;
      gll16(&x1bf[(size_t)(row0 + rb + srow)*D_ + k0 + skel], &As[rb*64]);
      gll16(&w1T [(size_t)(col0 + rb + srow)*D_ + k0 + skel], &Bs[rb*64]);
    }
    __syncthreads();
    #pragma unroll
    for (int kk = 0; kk < 2; ++kk) {
      int kb = (kk*64 + lk*16) ^ ((lr & 7) << 4);
      bf16x8 a[4];
      #pragma unroll
      for (int mf = 0; mf < 4; ++mf)
        a[mf] = *(const bf16x8*)((const char*)As + (wm*64 + mf*16 + lr)*128 + kb);
      #pragma unroll
      for (int nf = 0; nf < 4; ++nf) {
        bf16x8 bfr = *(const bf16x8*)((const char*)Bs + (wn*64 + nf*16 + lr)*128 + kb);
        #pragma unroll
        for (int mf = 0; mf < 4; ++mf)
          acc[mf][nf] = __builtin_amdgcn_mfma_f32_16x16x32_bf16(a[mf], bfr, acc[mf][nf], 0, 0, 0);
      }
    }
  }
  // ---- epilogue: tanh + w2-dot, shfl reduce, cross-wn combine ----
  #pragma unroll
  for (int mf = 0; mf < 4; ++mf) {
    #pragma unroll
    for (int r = 0; r < 4; ++r) {
      int rowt = wm*64 + mf*16 + lk*4 + r;
      float z0=0.f, z1=0.f, z2=0.f, z3=0.f;
      #pragma unroll
      for (int nf = 0; nf < 4; ++nf) {
        float t = ftanh(acc[mf][nf][r]);
        z0 += t * w2r[nf][0]; z1 += t * w2r[nf][1];
        z2 += t * w2r[nf][2]; z3 += t * w2r[nf][3];
      }
      #pragma unroll
      for (int msk = 1; msk <= 8; msk <<= 1) {
        z0 += __shfl_xor(z0, msk); z1 += __shfl_xor(z1, msk);
        z2 += __shfl_xor(z2, msk); z3 += __shfl_xor(z3, msk);
      }
      if (lr == 0)
        *(float4*)&zred[(wn*128 + rowt)*4] = make_float4(z0, z1, z2, z3);
    }
  }
  __syncthreads();
  if (tid < 128) {
    float4 s0 = *(float4*)&zred[tid*4];
    float4 s1 = *(float4*)&zred[(128 + tid)*4];
    *(float4*)&Zp[((size_t)colb*M_ + row0 + tid)*4] =
        make_float4(s0.x+s1.x, s0.y+s1.y, s0.z+s1.z, s0.w+s1.w);
  }
}

// K5: wave-per-batch. Sums 4 Zp partials; in-wave softmax; bf16x8 pooling;
// LN2 -> Hh2 bf16 + head-mean f32.
__global__ __launch_bounds__(512) void k5_attn(
    const float* __restrict__ Zp, const float* __restrict__ b2,
    const unsigned char* __restrict__ amask, const u16* __restrict__ x1bf,
    const float* __restrict__ mpx, const float* __restrict__ g2,
    const float* __restrict__ bln2, u16* __restrict__ Hh2bf,
    float* __restrict__ hmean) {
  __shared__ float abuf[8][120];
  int tid = threadIdx.x;
  int wid = tid >> 6, lane = tid & 63;
  int b = blockIdx.x*8 + wid;
  bool act = lane < N_;
  int tok = b*N_ + (act ? lane : 0);
  float zz[4] = {-INFINITY, -INFINITY, -INFINITY, -INFINITY};
  if (act) {
    float4 za = *(const float4*)&Zp[(size_t)tok*4];
    float4 zb = *(const float4*)&Zp[((size_t)M_ + tok)*4];
    float4 zc = *(const float4*)&Zp[((size_t)2*M_ + tok)*4];
    float4 zd = *(const float4*)&Zp[((size_t)3*M_ + tok)*4];
    float4 bv = *(const float4*)b2;
    zz[0] = za.x+zb.x+zc.x+zd.x+bv.x; zz[1] = za.y+zb.y+zc.y+zd.y+bv.y;
    zz[2] = za.z+zb.z+zc.z+zd.z+bv.z; zz[3] = za.w+zb.w+zc.w+zd.w+bv.w;
    if (amask[tok]) { zz[0]=zz[1]=zz[2]=zz[3]=-INFINITY; }
  }
  float p[4];
  #pragma unroll
  for (int h = 0; h < 4; ++h) {
    float mx = wmax(zz[h]);
    float e = act ? __expf(zz[h] - mx) : 0.f;
    float s = wsum(e);
    p[h] = e / s;
  }
  if (act) *(float4*)&abuf[wid][lane*4] = make_float4(p[0], p[1], p[2], p[3]);
  __syncthreads();
  float hv[4][8] = {};
  const u16* xr = &x1bf[(size_t)b*N_*D_ + lane*8];
  for (int j = 0; j < N_; ++j) {
    bf16x8 xb = *(const bf16x8*)(xr + (size_t)j*D_);
    float xv[8];
    #pragma unroll
    for (int e = 0; e < 8; ++e) xv[e] = bf2f((u16)xb[e]);
    #pragma unroll
    for (int i = 0; i < 4; ++i) {
      float a = abuf[wid][i*N_ + j];
      #pragma unroll
      for (int e = 0; e < 8; ++e) hv[i][e] += a * xv[e];
    }
  }
  float mpxv[8];
  *(float4*)&mpxv[0] = *(const float4*)&mpx[(size_t)b*D_ + lane*8];
  *(float4*)&mpxv[4] = *(const float4*)&mpx[(size_t)b*D_ + lane*8 + 4];
  float s1 = 0.f, s2 = 0.f;
  #pragma unroll
  for (int i = 0; i < 4; ++i)
    #pragma unroll
    for (int e = 0; e < 8; ++e) {
      hv[i][e] += mpxv[e];
      s1 += hv[i][e];
      s2 += hv[i][e]*hv[i][e];
    }
  s1 = wsum(s1); s2 = wsum(s2);
  float mu = s1 * (1.f/2048.f);
  float var = s2 * (1.f/2048.f) - mu*mu;
  float rs = 1.f / sqrtf(var + 1e-5f);
  float hm[8] = {0,0,0,0,0,0,0,0};
  #pragma unroll
  for (int i = 0; i < 4; ++i) {
    int idx = i*D_ + lane*8;
    float gg[8], bb[8];
    *(float4*)&gg[0] = *(const float4*)&g2[idx];
    *(float4*)&gg[4] = *(const float4*)&g2[idx+4];
    *(float4*)&bb[0] = *(const float4*)&bln2[idx];
    *(float4*)&bb[4] = *(const float4*)&bln2[idx+4];
    bf16x8 ob;
    #pragma unroll
    for (int e = 0; e < 8; ++e) {
      float v = gg[e]*((hv[i][e]-mu)*rs) + bb[e];
      hm[e] += v;
      ob[e] = (short)f2bf(v);
    }
    *(bf16x8*)&Hh2bf[(size_t)b*2048 + idx] = ob;
  }
  #pragma unroll
  for (int e = 0; e < 8; ++e) hm[e] *= 0.25f;
  *(float4*)&hmean[(size_t)b*D_ + lane*8]     = *(float4*)&hm[0];
  *(float4*)&hmean[(size_t)b*D_ + lane*8 + 4] = *(float4*)&hm[4];
}

// K6: fc2 GEMM 128x128 tile, BK=64, split-K=4 -> 512 blocks.
__global__ __launch_bounds__(256, 3) void k6_fc2(
    const u16* __restrict__ Hh2bf, const u16* __restrict__ fwT,
    float* __restrict__ pred_p) {
  __shared__ __align__(16) u16 As[128*64];
  __shared__ __align__(16) u16 Bs[128*64];
  int tid = threadIdx.x;
  int lane = tid & 63, wid = tid >> 6;
  int wg = (blockIdx.x & 7)*64 + (blockIdx.x >> 3);
  int kz = wg >> 7;
  int rem = wg & 127;
  int rowb = rem >> 2, colb = rem & 3;
  int row0 = rowb*128, col0 = colb*128;
  int kbase = kz*512;
  int wm = wid >> 1, wn = wid & 1;
  int lr = lane & 15, lk = lane >> 4;
  int srow = lane >> 3;
  int skel = ((lane & 7) ^ srow) << 3;
  f32x4 acc[4][4] = {};
  for (int k0 = kbase; k0 < kbase + 512; k0 += 64) {
    __syncthreads();
    #pragma unroll
    for (int i = 0; i < 4; ++i) {
      int rb = wid*32 + i*8;
      gll16(&Hh2bf[(size_t)(row0 + rb + srow)*2048 + k0 + skel], &As[rb*64]);
      gll16(&fwT  [(size_t)(col0 + rb + srow)*2048 + k0 + skel], &Bs[rb*64]);
    }
    __syncthreads();
    #pragma unroll
    for (int kk = 0; kk < 2; ++kk) {
      int kb = (kk*64 + lk*16) ^ ((lr & 7) << 4);
      bf16x8 a[4];
      #pragma unroll
      for (int mf = 0; mf < 4; ++mf)
        a[mf] = *(const bf16x8*)((const char*)As + (wm*64 + mf*16 + lr)*128 + kb);
      #pragma unroll
      for (int nf = 0; nf < 4; ++nf) {
        bf16x8 bfr = *(const bf16x8*)((const char*)Bs + (wn*64 + nf*16 + lr)*128 + kb);
        #pragma unroll
        for (int mf = 0; mf < 4; ++mf)
          acc[mf][nf] = __builtin_amdgcn_mfma_f32_16x16x32_bf16(a[mf], bfr, acc[mf][nf], 0, 0, 0);
      }
    }
  }
  float* dst = pred_p + (size_t)kz * B_ * D_;
  #pragma unroll
  for (int mf = 0; mf < 4; ++mf)
    #pragma unroll
    for (int nf = 0; nf < 4; ++nf)
      #pragma unroll
      for (int r = 0; r < 4; ++r) {
        int m = row0 + wm*64 + mf*16 + lk*4 + r;
        int j = col0 + wn*64 + nf*16 + lr;
        dst[(size_t)m*D_ + j] = acc[mf][nf][r];
      }
}

// K7: combine 4 split-K partials + fb, LN3, + head-mean, LN4 -> out
__global__ __launch_bounds__(512) void k7_final(
    const float* __restrict__ pred_p, const float* __restrict__ hmean,
    const float* __restrict__ fb,
    const float* __restrict__ g3, const float* __restrict__ b3,
    const float* __restrict__ g4, const float* __restrict__ b4,
    float* __restrict__ out) {
  __shared__ float red[8];
  int b = blockIdx.x, d = threadIdx.x;
  size_t i = (size_t)b*D_ + d;
  size_t BD = (size_t)B_*D_;
  float p = pred_p[i] + pred_p[BD + i] + pred_p[2*BD + i] + pred_p[3*BD + i]
          + fb[d];
  float s1 = bsum512(p, red);
  float s2 = bsum512(p*p, red);
  float mu = s1*(1.f/D_);
  float var = s2*(1.f/D_) - mu*mu;
  float p3 = g3[d]*((p-mu)/sqrtf(var+1e-5f)) + b3[d];
  float q = p3 + hmean[i];
  s1 = bsum512(q, red);
  s2 = bsum512(q*q, red);
  mu = s1*(1.f/D_);
  var = s2*(1.f/D_) - mu*mu;
  out[i] = g4[d]*((q-mu)/sqrtf(var+1e-5f)) + b4[d];
}

extern "C" void kernel_launch(void* const* d_in, const int* in_sizes, int n_in,
                              void* d_out, int out_size, void* d_ws, size_t ws_size,
                              hipStream_t stream) {
  const float* x      = (const float*)d_in[0];
  const unsigned char* amask = (const unsigned char*)d_in[1];
  const int*   order  = (const int*)d_in[2];
  const float* ndocs  = (const float*)d_in[3];
  const float* dw     = (const float*)d_in[4];
  const float* pe     = (const float*)d_in[6];
  const float* w1     = (const float*)d_in[7];
  const float* b1     = (const float*)d_in[8];
  const float* w2     = (const float*)d_in[9];
  const float* b2     = (const float*)d_in[10];
  const float* fw     = (const float*)d_in[11];
  const float* fb     = (const float*)d_in[12];
  const float* g1     = (const float*)d_in[13];
  const float* bln1   = (const float*)d_in[14];
  const float* g2     = (const float*)d_in[15];
  const float* bln2   = (const float*)d_in[16];
  const float* g3     = (const float*)d_in[17];
  const float* b3     = (const float*)d_in[18];
  const float* g4     = (const float*)d_in[19];
  const float* b4     = (const float*)d_in[20];
  float* out = (float*)d_out;

  char* ws = (char*)d_ws;
  size_t off = 0;
  u16*   x1bf   = (u16*)(ws + off);   off += (size_t)M_*D_*2;        // 125.8 MB
  u16*   mpbf   = (u16*)(ws + off);   off += (size_t)B_*D_*2;        // 4.2 MB
  float* mpx    = (float*)(ws + off); off += (size_t)B_*D_*4;        // 8.4 MB
  float* mpW    = (float*)(ws + off); off += (size_t)B_*D_*4;        // 8.4 MB
  float* hmean  = (float*)(ws + off); off += (size_t)B_*D_*4;        // 8.4 MB
  float* peW    = (float*)(ws + off); off += (size_t)PE_ROWS*D_*4;
  float* cosb   = (float*)(ws + off); off += (size_t)M_*4;
  float* Zp     = (float*)(ws + off); off += (size_t)4*M_*4*4;       // 7.9 MB
  float* pred_p = (float*)(ws + off); off += (size_t)4*B_*D_*4;      // 33.6 MB
  u16*   Hh2bf  = (u16*)(ws + off);   off += (size_t)B_*2048*2;      // 16.8 MB
  u16*   w1T    = (u16*)(ws + off);   off += (size_t)D_*D_*2;        // 0.5 MB
  u16*   w1mT   = (u16*)(ws + off);   off += (size_t)D_*D_*2;        // 0.5 MB
  u16*   fwT    = (u16*)(ws + off);   off += (size_t)D_*2048*2;      // 2.1 MB
  (void)ws_size; (void)in_sizes; (void)n_in; (void)out_size;

  k_tcvt<<<dim3(8, 8), 256, 0, stream>>>(w1, w1T, 512, 512);        // W_top^T
  k_tcvt<<<dim3(8, 8), 256, 0, stream>>>(w1 + 512*512, w1mT, 512, 512); // W_mid^T
  k_tcvt<<<dim3(32, 8), 256, 0, stream>>>(fw, fwT, 2048, 512);      // fc2_w^T
  k_pew<<<PE_ROWS, 512, 0, stream>>>(pe, w1, peW);
  k1_prep<<<B_, 512, 0, stream>>>(x, order, ndocs, dw, pe, g1, bln1,
                                  x1bf, mpbf, mpx, cosb);
  k2_mpw<<<128, 256, 0, stream>>>(mpbf, w1mT, b1, mpW);
  k4_fc1<<<3840, 256, 0, stream>>>(x1bf, w1T, w1, w2, order, cosb,
                                   mpW, peW, Zp);
  k5_attn<<<B_/8, 512, 0, stream>>>(Zp, b2, amask, x1bf, mpx, g2, bln2,
                                    Hh2bf, hmean);
  k6_fc2<<<512, 256, 0, stream>>>(Hh2bf, fwT, pred_p);
  k7_final<<<B_, 512, 0, stream>>>(pred_p, hmean, fb, g3, b3, g4, b4, out);
}

// Round 9
// 325.910 us; speedup vs baseline: 2.7484x; 1.3153x over previous
//
#include <hip/hip_runtime.h>
#include <hip/hip_bf16.h>

#define B_ 4096
#define N_ 30
#define D_ 512
#define H_ 4
#define M_ (B_*N_)      // 122880 tokens
#define PE_ROWS 31

typedef unsigned short u16;
typedef __attribute__((ext_vector_type(8))) short bf16x8;
typedef __attribute__((ext_vector_type(4))) float f32x4;

__device__ __forceinline__ float bf2f(u16 s) { return __uint_as_float(((unsigned)s) << 16); }
__device__ __forceinline__ u16 f2bf(float f) {
  __hip_bfloat16 h = __float2bfloat16(f);
  return *reinterpret_cast<u16*>(&h);
}

// fast tanh: 1 - 2/(exp(2x)+1)
__device__ __forceinline__ float ftanh(float x) {
  float e = __expf(2.f * x);
  return 1.f - 2.f * __builtin_amdgcn_rcpf(e + 1.f);
}

// async global->LDS, 16B per lane. LDS dest = wave-uniform base + lane*16.
__device__ __forceinline__ void gll16(const void* g, void* l) {
  __builtin_amdgcn_global_load_lds(
      (const __attribute__((address_space(1))) unsigned int*)g,
      (__attribute__((address_space(3))) unsigned int*)l, 16, 0, 0);
}

// full-wave (64-lane) sum / max
__device__ __forceinline__ float wsum(float v) {
  #pragma unroll
  for (int m = 32; m >= 1; m >>= 1) v += __shfl_xor(v, m);
  return v;
}
__device__ __forceinline__ float wmax(float v) {
  #pragma unroll
  for (int m = 32; m >= 1; m >>= 1) v = fmaxf(v, __shfl_xor(v, m));
  return v;
}

// K1: wave-per-token prep (normalize -> LN1 -> +pos_emb, pools, cosine).
__global__ __launch_bounds__(512) void k1_prep(
    const float* __restrict__ x, const int* __restrict__ order,
    const float* __restrict__ ndocs, const float* __restrict__ dw,
    const float* __restrict__ pe, const float* __restrict__ g1,
    const float* __restrict__ bln1,
    u16* __restrict__ x1bf, u16* __restrict__ mpbf, float* __restrict__ mpx,
    float* __restrict__ cosb) {
  __shared__ float lds_mp[8*512];
  __shared__ float lds_mpx[8*512];
  __shared__ float xps[32];
  int b = blockIdx.x;
  int tid = threadIdx.x;
  int wid = tid >> 6, lane = tid & 63;
  int d0 = lane * 8;
  float g[8], bl[8];
  *(float4*)&g[0]  = *(const float4*)&g1[d0];
  *(float4*)&g[4]  = *(const float4*)&g1[d0+4];
  *(float4*)&bl[0] = *(const float4*)&bln1[d0];
  *(float4*)&bl[4] = *(const float4*)&bln1[d0+4];
  float xp_reg[4][8];
  float accmp[8] = {0,0,0,0,0,0,0,0}, accmpx[8] = {0,0,0,0,0,0,0,0};
  #pragma unroll
  for (int t = 0; t < 4; ++t) {
    int n = wid + 8*t;
    if (n < N_) {
      int tok = b*N_ + n;
      float v[8];
      *(float4*)&v[0] = *(const float4*)&x[(size_t)tok*D_ + d0];
      *(float4*)&v[4] = *(const float4*)&x[(size_t)tok*D_ + d0 + 4];
      float ss = 0.f, sm = 0.f;
      #pragma unroll
      for (int i = 0; i < 8; ++i) { ss += v[i]*v[i]; sm += v[i]; }
      ss = wsum(ss); sm = wsum(sm);
      float inv = 1.f / fmaxf(sqrtf(ss), 1e-8f);
      float mu = sm * inv * (1.f/D_);
      float m2 = ss*inv*inv*(1.f/D_);
      float rs = 1.f / sqrtf(m2 - mu*mu + 1e-5f);
      int o = order[tok];
      float p8[8];
      *(float4*)&p8[0] = *(const float4*)&pe[(size_t)o*D_ + d0];
      *(float4*)&p8[4] = *(const float4*)&pe[(size_t)o*D_ + d0 + 4];
      float wv = dw[tok];
      float sq = 0.f;
      bf16x8 xb;
      #pragma unroll
      for (int i = 0; i < 8; ++i) {
        float x1v = g[i]*((v[i]*inv - mu)*rs) + bl[i];
        xb[i] = (short)f2bf(x1v);
        float xpv = x1v + p8[i];
        xp_reg[t][i] = xpv;
        accmp[i]  += wv*xpv;
        accmpx[i] += wv*x1v;
        sq += xpv*xpv;
      }
      *(bf16x8*)&x1bf[(size_t)tok*D_ + d0] = xb;
      sq = wsum(sq);
      if (lane == 0) xps[n] = sq;
    }
  }
  #pragma unroll
  for (int i = 0; i < 8; i += 4) {
    *(float4*)&lds_mp[wid*512 + d0 + i]  = *(float4*)&accmp[i];
    *(float4*)&lds_mpx[wid*512 + d0 + i] = *(float4*)&accmpx[i];
  }
  __syncthreads();
  float invnd = 1.f / ndocs[b];
  float mpv[8] = {0,0,0,0,0,0,0,0}, mpxv[8] = {0,0,0,0,0,0,0,0};
  #pragma unroll
  for (int w = 0; w < 8; ++w) {
    #pragma unroll
    for (int i = 0; i < 8; i += 4) {
      float4 a = *(float4*)&lds_mp[w*512 + d0 + i];
      mpv[i+0] += a.x; mpv[i+1] += a.y; mpv[i+2] += a.z; mpv[i+3] += a.w;
      float4 c = *(float4*)&lds_mpx[w*512 + d0 + i];
      mpxv[i+0] += c.x; mpxv[i+1] += c.y; mpxv[i+2] += c.z; mpxv[i+3] += c.w;
    }
  }
  #pragma unroll
  for (int i = 0; i < 8; ++i) { mpv[i] *= invnd; mpxv[i] *= invnd; }
  if (wid == 0) {
    bf16x8 mb;
    #pragma unroll
    for (int i = 0; i < 8; ++i) mb[i] = (short)f2bf(mpv[i]);
    *(bf16x8*)&mpbf[(size_t)b*D_ + d0] = mb;
  }
  if (wid == 1) {
    #pragma unroll
    for (int i = 0; i < 8; i += 4)
      *(float4*)&mpx[(size_t)b*D_ + d0 + i] = *(float4*)&mpxv[i];
  }
  float mn = 0.f;
  #pragma unroll
  for (int i = 0; i < 8; ++i) mn += mpv[i]*mpv[i];
  float mpn = sqrtf(wsum(mn));
  #pragma unroll
  for (int t = 0; t < 4; ++t) {
    int n = wid + 8*t;
    if (n < N_) {
      float dot = 0.f;
      #pragma unroll
      for (int i = 0; i < 8; ++i) dot += mpv[i]*xp_reg[t][i];
      dot = wsum(dot);
      if (lane == 0)
        cosb[b*N_ + n] = dot / fmaxf(mpn * sqrtf(xps[n]), 1e-8f);
    }
  }
}

// peW[p][j] = pos_emb[p] @ W_top   (31 x 512)
__global__ __launch_bounds__(512) void k_pew(
    const float* __restrict__ pe, const float* __restrict__ w1,
    float* __restrict__ peW) {
  int p = blockIdx.x, j = threadIdx.x;
  float acc = 0.f;
  for (int dd = 0; dd < D_; ++dd) acc += pe[p*D_ + dd] * w1[(size_t)dd*D_ + j];
  peW[p*D_ + j] = acc;
}

// Tiled transpose+convert: out[j][k] = bf16(in[k][j])
__global__ __launch_bounds__(256) void k_tcvt(
    const float* __restrict__ in, u16* __restrict__ out, int Kdim, int Jdim) {
  __shared__ float tile[64][65];
  int k0 = blockIdx.x * 64, j0 = blockIdx.y * 64;
  int t = threadIdx.x;
  int tr = t >> 4, tc4 = (t & 15) * 4;
  #pragma unroll
  for (int i = 0; i < 4; ++i) {
    int k = k0 + tr + i*16;
    float4 v = *(const float4*)&in[(size_t)k*Jdim + j0 + tc4];
    tile[tr + i*16][tc4+0] = v.x;
    tile[tr + i*16][tc4+1] = v.y;
    tile[tr + i*16][tc4+2] = v.z;
    tile[tr + i*16][tc4+3] = v.w;
  }
  __syncthreads();
  #pragma unroll
  for (int i = 0; i < 4; ++i) {
    int j = tr + i*16;
    uint2 u;
    u.x = (unsigned)f2bf(tile[tc4+0][j]) | ((unsigned)f2bf(tile[tc4+1][j]) << 16);
    u.y = (unsigned)f2bf(tile[tc4+2][j]) | ((unsigned)f2bf(tile[tc4+3][j]) << 16);
    *(uint2*)&out[(size_t)(j0+j)*Kdim + k0 + tc4] = u;
  }
}

// K2: mpW = mp @ W_mid + b1, MFMA 128x128 tile, BK=64, 128 blocks.
__global__ __launch_bounds__(256, 3) void k2_mpw(
    const u16* __restrict__ mpbf, const u16* __restrict__ w1mT,
    const float* __restrict__ b1, float* __restrict__ mpW) {
  __shared__ __align__(16) u16 As[128*64];
  __shared__ __align__(16) u16 Bs[128*64];
  int tid = threadIdx.x;
  int lane = tid & 63, wid = tid >> 6;
  int wg = (blockIdx.x & 7)*16 + (blockIdx.x >> 3);
  int colb = wg & 3, rowb = wg >> 2;
  int row0 = rowb*128, col0 = colb*128;
  int wm = wid >> 1, wn = wid & 1;
  int lr = lane & 15, lk = lane >> 4;
  int srow = lane >> 3;
  int skel = ((lane & 7) ^ srow) << 3;
  f32x4 acc[4][4];
  #pragma unroll
  for (int nf = 0; nf < 4; ++nf) {
    float bv = b1[col0 + wn*64 + nf*16 + lr];
    #pragma unroll
    for (int mf = 0; mf < 4; ++mf)
      acc[mf][nf] = (f32x4){bv, bv, bv, bv};
  }
  for (int k0 = 0; k0 < D_; k0 += 64) {
    __syncthreads();
    #pragma unroll
    for (int i = 0; i < 4; ++i) {
      int rb = wid*32 + i*8;
      gll16(&mpbf[(size_t)(row0 + rb + srow)*D_ + k0 + skel], &As[rb*64]);
      gll16(&w1mT[(size_t)(col0 + rb + srow)*D_ + k0 + skel], &Bs[rb*64]);
    }
    __syncthreads();
    #pragma unroll
    for (int kk = 0; kk < 2; ++kk) {
      int kb = (kk*64 + lk*16) ^ ((lr & 7) << 4);
      bf16x8 a[4];
      #pragma unroll
      for (int mf = 0; mf < 4; ++mf)
        a[mf] = *(const bf16x8*)((const char*)As + (wm*64 + mf*16 + lr)*128 + kb);
      #pragma unroll
      for (int nf = 0; nf < 4; ++nf) {
        bf16x8 bfr = *(const bf16x8*)((const char*)Bs + (wn*64 + nf*16 + lr)*128 + kb);
        #pragma unroll
        for (int mf = 0; mf < 4; ++mf)
          acc[mf][nf] = __builtin_amdgcn_mfma_f32_16x16x32_bf16(a[mf], bfr, acc[mf][nf], 0, 0, 0);
      }
    }
  }
  #pragma unroll
  for (int mf = 0; mf < 4; ++mf)
    #pragma unroll
    for (int nf = 0; nf < 4; ++nf)
      #pragma unroll
      for (int r = 0; r < 4; ++r) {
        int m = row0 + wm*64 + mf*16 + lk*4 + r;
        int j = col0 + wn*64 + nf*16 + lr;
        mpW[(size_t)m*D_ + j] = acc[mf][nf][r];
      }
}

// K4 v5 (exact round-6 revert; measured 143us): 128x128 m97-structure,
// 256 thr / 4 waves (2x2), BK=64, global_load_lds + both-sides swizzle,
// scattered acc-init (latency hidden under first staging), tanh+w2 epilogue.
__global__ __launch_bounds__(256, 3) void k4_fc1(
    const u16* __restrict__ x1bf, const u16* __restrict__ w1T,
    const float* __restrict__ w1, const float* __restrict__ w2,
    const int* __restrict__ order, const float* __restrict__ cosb,
    const float* __restrict__ mpW, const float* __restrict__ peW,
    float* __restrict__ Zp) {
  __shared__ __align__(16) u16 As[128*64];   // 16 KB
  __shared__ __align__(16) u16 Bs[128*64];   // 16 KB
  __shared__ float zred[2*128*4];            // 4 KB
  int tid = threadIdx.x;
  int lane = tid & 63, wid = tid >> 6;
  int col0 = blockIdx.x * 128;
  int row0 = blockIdx.y * 128;
  int wm = wid >> 1, wn = wid & 1;
  int lr = lane & 15, lk = lane >> 4;
  int srow = lane >> 3;                       // sub-row within 8-row group
  int skel = ((lane & 7) ^ srow) << 3;        // inverse-swizzled k element
  // acc init = mpW[bidx][jl] + peW[o][jl] + cs*w1_last[jl]
  float wl[4];
  #pragma unroll
  for (int nf = 0; nf < 4; ++nf)
    wl[nf] = w1[(size_t)1024*D_ + col0 + wn*64 + nf*16 + lr];
  f32x4 acc[4][4];
  #pragma unroll
  for (int mf = 0; mf < 4; ++mf) {
    #pragma unroll
    for (int r = 0; r < 4; ++r) {
      int m = row0 + wm*64 + mf*16 + lk*4 + r;
      int bidx = m / N_;
      int o = order[m];
      float cs = cosb[m];
      #pragma unroll
      for (int nf = 0; nf < 4; ++nf) {
        int jl = col0 + wn*64 + nf*16 + lr;
        acc[mf][nf][r] = mpW[(size_t)bidx*D_ + jl] + peW[o*D_ + jl] + cs*wl[nf];
      }
    }
  }
  for (int k0 = 0; k0 < D_; k0 += 64) {
    __syncthreads();                    // previous tile's reads complete
    #pragma unroll
    for (int i = 0; i < 4; ++i) {
      int rb = wid*32 + i*8;            // 8 rows per wave-load
      gll16(&x1bf[(size_t)(row0 + rb + srow)*D_ + k0 + skel], &As[rb*64]);
      gll16(&w1T [(size_t)(col0 + rb + srow)*D_ + k0 + skel], &Bs[rb*64]);
    }
    __syncthreads();                    // vmcnt(0) drained before barrier
    #pragma unroll
    for (int kk = 0; kk < 2; ++kk) {
      int kb = (kk*64 + lk*16) ^ ((lr & 7) << 4);
      bf16x8 a[4];
      #pragma unroll
      for (int mf = 0; mf < 4; ++mf)
        a[mf] = *(const bf16x8*)((const char*)As + (wm*64 + mf*16 + lr)*128 + kb);
      #pragma unroll
      for (int nf = 0; nf < 4; ++nf) {
        bf16x8 bfr = *(const bf16x8*)((const char*)Bs + (wn*64 + nf*16 + lr)*128 + kb);
        #pragma unroll
        for (int mf = 0; mf < 4; ++mf)
          acc[mf][nf] = __builtin_amdgcn_mfma_f32_16x16x32_bf16(a[mf], bfr, acc[mf][nf], 0, 0, 0);
      }
    }
  }
  // epilogue: tanh + w2-dot, reduce over 16-lane col groups
  float w2r[4][4];
  #pragma unroll
  for (int nf = 0; nf < 4; ++nf)
    *(float4*)w2r[nf] = *(const float4*)&w2[(col0 + wn*64 + nf*16 + lr)*4];
  #pragma unroll
  for (int mf = 0; mf < 4; ++mf) {
    #pragma unroll
    for (int r = 0; r < 4; ++r) {
      int rowt = wm*64 + mf*16 + lk*4 + r;
      float z0=0.f, z1=0.f, z2=0.f, z3=0.f;
      #pragma unroll
      for (int nf = 0; nf < 4; ++nf) {
        float t = ftanh(acc[mf][nf][r]);
        z0 += t * w2r[nf][0]; z1 += t * w2r[nf][1];
        z2 += t * w2r[nf][2]; z3 += t * w2r[nf][3];
      }
      #pragma unroll
      for (int msk = 1; msk <= 8; msk <<= 1) {
        z0 += __shfl_xor(z0, msk); z1 += __shfl_xor(z1, msk);
        z2 += __shfl_xor(z2, msk); z3 += __shfl_xor(z3, msk);
      }
      if (lr == 0)
        *(float4*)&zred[(wn*128 + rowt)*4] = make_float4(z0, z1, z2, z3);
    }
  }
  __syncthreads();
  if (tid < 128) {
    float4 s0 = *(float4*)&zred[tid*4];
    float4 s1 = *(float4*)&zred[(128 + tid)*4];
    *(float4*)&Zp[((size_t)blockIdx.x*M_ + row0 + tid)*4] =
        make_float4(s0.x+s1.x, s0.y+s1.y, s0.z+s1.z, s0.w+s1.w);
  }
}

// K5: wave-per-batch. Sums 4 Zp partials; in-wave softmax; bf16x8 pooling;
// LN2 -> Hh2 bf16 + head-mean f32.
__global__ __launch_bounds__(512) void k5_attn(
    const float* __restrict__ Zp, const float* __restrict__ b2,
    const unsigned char* __restrict__ amask, const u16* __restrict__ x1bf,
    const float* __restrict__ mpx, const float* __restrict__ g2,
    const float* __restrict__ bln2, u16* __restrict__ Hh2bf,
    float* __restrict__ hmean) {
  __shared__ float abuf[8][120];
  int tid = threadIdx.x;
  int wid = tid >> 6, lane = tid & 63;
  int b = blockIdx.x*8 + wid;
  bool act = lane < N_;
  int tok = b*N_ + (act ? lane : 0);
  float zz[4] = {-INFINITY, -INFINITY, -INFINITY, -INFINITY};
  if (act) {
    float4 za = *(const float4*)&Zp[(size_t)tok*4];
    float4 zb = *(const float4*)&Zp[((size_t)M_ + tok)*4];
    float4 zc = *(const float4*)&Zp[((size_t)2*M_ + tok)*4];
    float4 zd = *(const float4*)&Zp[((size_t)3*M_ + tok)*4];
    float4 bv = *(const float4*)b2;
    zz[0] = za.x+zb.x+zc.x+zd.x+bv.x; zz[1] = za.y+zb.y+zc.y+zd.y+bv.y;
    zz[2] = za.z+zb.z+zc.z+zd.z+bv.z; zz[3] = za.w+zb.w+zc.w+zd.w+bv.w;
    if (amask[tok]) { zz[0]=zz[1]=zz[2]=zz[3]=-INFINITY; }
  }
  float p[4];
  #pragma unroll
  for (int h = 0; h < 4; ++h) {
    float mx = wmax(zz[h]);
    float e = act ? __expf(zz[h] - mx) : 0.f;
    float s = wsum(e);
    p[h] = e / s;
  }
  if (act) *(float4*)&abuf[wid][lane*4] = make_float4(p[0], p[1], p[2], p[3]);
  __syncthreads();
  float hv[4][8] = {};
  const u16* xr = &x1bf[(size_t)b*N_*D_ + lane*8];
  for (int j = 0; j < N_; ++j) {
    bf16x8 xb = *(const bf16x8*)(xr + (size_t)j*D_);
    float xv[8];
    #pragma unroll
    for (int e = 0; e < 8; ++e) xv[e] = bf2f((u16)xb[e]);
    #pragma unroll
    for (int i = 0; i < 4; ++i) {
      float a = abuf[wid][i*N_ + j];
      #pragma unroll
      for (int e = 0; e < 8; ++e) hv[i][e] += a * xv[e];
    }
  }
  float mpxv[8];
  *(float4*)&mpxv[0] = *(const float4*)&mpx[(size_t)b*D_ + lane*8];
  *(float4*)&mpxv[4] = *(const float4*)&mpx[(size_t)b*D_ + lane*8 + 4];
  float s1 = 0.f, s2 = 0.f;
  #pragma unroll
  for (int i = 0; i < 4; ++i)
    #pragma unroll
    for (int e = 0; e < 8; ++e) {
      hv[i][e] += mpxv[e];
      s1 += hv[i][e];
      s2 += hv[i][e]*hv[i][e];
    }
  s1 = wsum(s1); s2 = wsum(s2);
  float mu = s1 * (1.f/2048.f);
  float var = s2 * (1.f/2048.f) - mu*mu;
  float rs = 1.f / sqrtf(var + 1e-5f);
  float hm[8] = {0,0,0,0,0,0,0,0};
  #pragma unroll
  for (int i = 0; i < 4; ++i) {
    int idx = i*D_ + lane*8;
    float gg[8], bb[8];
    *(float4*)&gg[0] = *(const float4*)&g2[idx];
    *(float4*)&gg[4] = *(const float4*)&g2[idx+4];
    *(float4*)&bb[0] = *(const float4*)&bln2[idx];
    *(float4*)&bb[4] = *(const float4*)&bln2[idx+4];
    bf16x8 ob;
    #pragma unroll
    for (int e = 0; e < 8; ++e) {
      float v = gg[e]*((hv[i][e]-mu)*rs) + bb[e];
      hm[e] += v;
      ob[e] = (short)f2bf(v);
    }
    *(bf16x8*)&Hh2bf[(size_t)b*2048 + idx] = ob;
  }
  #pragma unroll
  for (int e = 0; e < 8; ++e) hm[e] *= 0.25f;
  *(float4*)&hmean[(size_t)b*D_ + lane*8]     = *(float4*)&hm[0];
  *(float4*)&hmean[(size_t)b*D_ + lane*8 + 4] = *(float4*)&hm[4];
}

// K6: fc2 GEMM 128x128 tile, BK=64, split-K=4 -> 512 blocks.
__global__ __launch_bounds__(256, 3) void k6_fc2(
    const u16* __restrict__ Hh2bf, const u16* __restrict__ fwT,
    float* __restrict__ pred_p) {
  __shared__ __align__(16) u16 As[128*64];
  __shared__ __align__(16) u16 Bs[128*64];
  int tid = threadIdx.x;
  int lane = tid & 63, wid = tid >> 6;
  int wg = (blockIdx.x & 7)*64 + (blockIdx.x >> 3);
  int kz = wg >> 7;
  int rem = wg & 127;
  int rowb = rem >> 2, colb = rem & 3;
  int row0 = rowb*128, col0 = colb*128;
  int kbase = kz*512;
  int wm = wid >> 1, wn = wid & 1;
  int lr = lane & 15, lk = lane >> 4;
  int srow = lane >> 3;
  int skel = ((lane & 7) ^ srow) << 3;
  f32x4 acc[4][4] = {};
  for (int k0 = kbase; k0 < kbase + 512; k0 += 64) {
    __syncthreads();
    #pragma unroll
    for (int i = 0; i < 4; ++i) {
      int rb = wid*32 + i*8;
      gll16(&Hh2bf[(size_t)(row0 + rb + srow)*2048 + k0 + skel], &As[rb*64]);
      gll16(&fwT  [(size_t)(col0 + rb + srow)*2048 + k0 + skel], &Bs[rb*64]);
    }
    __syncthreads();
    #pragma unroll
    for (int kk = 0; kk < 2; ++kk) {
      int kb = (kk*64 + lk*16) ^ ((lr & 7) << 4);
      bf16x8 a[4];
      #pragma unroll
      for (int mf = 0; mf < 4; ++mf)
        a[mf] = *(const bf16x8*)((const char*)As + (wm*64 + mf*16 + lr)*128 + kb);
      #pragma unroll
      for (int nf = 0; nf < 4; ++nf) {
        bf16x8 bfr = *(const bf16x8*)((const char*)Bs + (wn*64 + nf*16 + lr)*128 + kb);
        #pragma unroll
        for (int mf = 0; mf < 4; ++mf)
          acc[mf][nf] = __builtin_amdgcn_mfma_f32_16x16x32_bf16(a[mf], bfr, acc[mf][nf], 0, 0, 0);
      }
    }
  }
  float* dst = pred_p + (size_t)kz * B_ * D_;
  #pragma unroll
  for (int mf = 0; mf < 4; ++mf)
    #pragma unroll
    for (int nf = 0; nf < 4; ++nf)
      #pragma unroll
      for (int r = 0; r < 4; ++r) {
        int m = row0 + wm*64 + mf*16 + lk*4 + r;
        int j = col0 + wn*64 + nf*16 + lr;
        dst[(size_t)m*D_ + j] = acc[mf][nf][r];
      }
}

// K7 v2: wave-per-row. Combine 4 split-K partials + fb, LN3 (in-wave),
// + head-mean, LN4 (in-wave) -> out. No barriers.
__global__ __launch_bounds__(512) void k7_final(
    const float* __restrict__ pred_p, const float* __restrict__ hmean,
    const float* __restrict__ fb,
    const float* __restrict__ g3, const float* __restrict__ b3,
    const float* __restrict__ g4, const float* __restrict__ b4,
    float* __restrict__ out) {
  int tid = threadIdx.x;
  int wid = tid >> 6, lane = tid & 63;
  int b = blockIdx.x*8 + wid;
  int d0 = lane*8;
  size_t i = (size_t)b*D_ + d0;
  size_t BD = (size_t)B_*D_;
  float p[8];
  #pragma unroll
  for (int e = 0; e < 8; e += 4) {
    float4 a0 = *(const float4*)&pred_p[i+e];
    float4 a1 = *(const float4*)&pred_p[BD+i+e];
    float4 a2 = *(const float4*)&pred_p[2*BD+i+e];
    float4 a3 = *(const float4*)&pred_p[3*BD+i+e];
    float4 fv = *(const float4*)&fb[d0+e];
    p[e+0] = a0.x+a1.x+a2.x+a3.x+fv.x;
    p[e+1] = a0.y+a1.y+a2.y+a3.y+fv.y;
    p[e+2] = a0.z+a1.z+a2.z+a3.z+fv.z;
    p[e+3] = a0.w+a1.w+a2.w+a3.w+fv.w;
  }
  float s1 = 0.f, s2 = 0.f;
  #pragma unroll
  for (int e = 0; e < 8; ++e) { s1 += p[e]; s2 += p[e]*p[e]; }
  s1 = wsum(s1); s2 = wsum(s2);
  float mu = s1*(1.f/D_);
  float var = s2*(1.f/D_) - mu*mu;
  float rs = 1.f / sqrtf(var + 1e-5f);
  float g3v[8], b3v[8], hmv[8], q[8];
  *(float4*)&g3v[0] = *(const float4*)&g3[d0];
  *(float4*)&g3v[4] = *(const float4*)&g3[d0+4];
  *(float4*)&b3v[0] = *(const float4*)&b3[d0];
  *(float4*)&b3v[4] = *(const float4*)&b3[d0+4];
  *(float4*)&hmv[0] = *(const float4*)&hmean[i];
  *(float4*)&hmv[4] = *(const float4*)&hmean[i+4];
  float t1 = 0.f, t2 = 0.f;
  #pragma unroll
  for (int e = 0; e < 8; ++e) {
    q[e] = g3v[e]*((p[e]-mu)*rs) + b3v[e] + hmv[e];
    t1 += q[e]; t2 += q[e]*q[e];
  }
  t1 = wsum(t1); t2 = wsum(t2);
  mu = t1*(1.f/D_);
  var = t2*(1.f/D_) - mu*mu;
  rs = 1.f / sqrtf(var + 1e-5f);
  float g4v[8], b4v[8], o[8];
  *(float4*)&g4v[0] = *(const float4*)&g4[d0];
  *(float4*)&g4v[4] = *(const float4*)&g4[d0+4];
  *(float4*)&b4v[0] = *(const float4*)&b4[d0];
  *(float4*)&b4v[4] = *(const float4*)&b4[d0+4];
  #pragma unroll
  for (int e = 0; e < 8; ++e) o[e] = g4v[e]*((q[e]-mu)*rs) + b4v[e];
  *(float4*)&out[i]   = *(float4*)&o[0];
  *(float4*)&out[i+4] = *(float4*)&o[4];
}

extern "C" void kernel_launch(void* const* d_in, const int* in_sizes, int n_in,
                              void* d_out, int out_size, void* d_ws, size_t ws_size,
                              hipStream_t stream) {
  const float* x      = (const float*)d_in[0];
  const unsigned char* amask = (const unsigned char*)d_in[1];
  const int*   order  = (const int*)d_in[2];
  const float* ndocs  = (const float*)d_in[3];
  const float* dw     = (const float*)d_in[4];
  const float* pe     = (const float*)d_in[6];
  const float* w1     = (const float*)d_in[7];
  const float* b1     = (const float*)d_in[8];
  const float* w2     = (const float*)d_in[9];
  const float* b2     = (const float*)d_in[10];
  const float* fw     = (const float*)d_in[11];
  const float* fb     = (const float*)d_in[12];
  const float* g1     = (const float*)d_in[13];
  const float* bln1   = (const float*)d_in[14];
  const float* g2     = (const float*)d_in[15];
  const float* bln2   = (const float*)d_in[16];
  const float* g3     = (const float*)d_in[17];
  const float* b3     = (const float*)d_in[18];
  const float* g4     = (const float*)d_in[19];
  const float* b4     = (const float*)d_in[20];
  float* out = (float*)d_out;

  char* ws = (char*)d_ws;
  size_t off = 0;
  u16*   x1bf   = (u16*)(ws + off);   off += (size_t)M_*D_*2;        // 125.8 MB
  u16*   mpbf   = (u16*)(ws + off);   off += (size_t)B_*D_*2;        // 4.2 MB
  float* mpx    = (float*)(ws + off); off += (size_t)B_*D_*4;        // 8.4 MB
  float* mpW    = (float*)(ws + off); off += (size_t)B_*D_*4;        // 8.4 MB
  float* hmean  = (float*)(ws + off); off += (size_t)B_*D_*4;        // 8.4 MB
  float* peW    = (float*)(ws + off); off += (size_t)PE_ROWS*D_*4;
  float* cosb   = (float*)(ws + off); off += (size_t)M_*4;
  float* Zp     = (float*)(ws + off); off += (size_t)4*M_*4*4;       // 7.9 MB
  float* pred_p = (float*)(ws + off); off += (size_t)4*B_*D_*4;      // 33.6 MB
  u16*   Hh2bf  = (u16*)(ws + off);   off += (size_t)B_*2048*2;      // 16.8 MB
  u16*   w1T    = (u16*)(ws + off);   off += (size_t)D_*D_*2;        // 0.5 MB
  u16*   w1mT   = (u16*)(ws + off);   off += (size_t)D_*D_*2;        // 0.5 MB
  u16*   fwT    = (u16*)(ws + off);   off += (size_t)D_*2048*2;      // 2.1 MB
  (void)ws_size; (void)in_sizes; (void)n_in; (void)out_size;

  k_tcvt<<<dim3(8, 8), 256, 0, stream>>>(w1, w1T, 512, 512);        // W_top^T
  k_tcvt<<<dim3(8, 8), 256, 0, stream>>>(w1 + 512*512, w1mT, 512, 512); // W_mid^T
  k_tcvt<<<dim3(32, 8), 256, 0, stream>>>(fw, fwT, 2048, 512);      // fc2_w^T
  k_pew<<<PE_ROWS, 512, 0, stream>>>(pe, w1, peW);
  k1_prep<<<B_, 512, 0, stream>>>(x, order, ndocs, dw, pe, g1, bln1,
                                  x1bf, mpbf, mpx, cosb);
  k2_mpw<<<128, 256, 0, stream>>>(mpbf, w1mT, b1, mpW);
  k4_fc1<<<dim3(4, M_/128), 256, 0, stream>>>(x1bf, w1T, w1, w2, order, cosb,
                                              mpW, peW, Zp);
  k5_attn<<<B_/8, 512, 0, stream>>>(Zp, b2, amask, x1bf, mpx, g2, bln2,
                                    Hh2bf, hmean);
  k6_fc2<<<512, 256, 0, stream>>>(Hh2bf, fwT, pred_p);
  k7_final<<<B_/8, 512, 0, stream>>>(pred_p, hmean, fb, g3, b3, g4, b4, out);
}